// Round 1
// baseline (3409.513 us; speedup 1.0000x reference)
//
#include <hip/hip_runtime.h>

// Problem sizes
#define Bn 1024
#define Tn 168
#define En 8
#define Hn 512
#define Dn 4
#define On 24
#define G4 2048            // 4*H
#define HB (Bn*Hn)         // elements per h buffer plane

typedef short v8s __attribute__((ext_vector_type(8)));
typedef float v4f __attribute__((ext_vector_type(4)));

__device__ __forceinline__ unsigned short f2bf(float f) {
  union { float f; unsigned u; } v; v.f = f;
  return (unsigned short)((v.u + 0x7fffu + ((v.u >> 16) & 1u)) >> 16);
}
__device__ __forceinline__ float bf2f(unsigned short s) {
  union { unsigned u; float f; } v; v.u = ((unsigned)s) << 16; return v.f;
}
__device__ __forceinline__ float sigm(float x) { return 1.f / (1.f + __expf(-x)); }
__device__ __forceinline__ float tanh_(float x) { return 1.f - 2.f / (__expf(2.f * x) + 1.f); }

// ---------------- setup kernels ----------------

// bf16-convert W_hh_enc; build W_eff = W_hh_dec + W_ih_dec @ W_fc (bf16)
__global__ void setup_weights(const float* __restrict__ whh_enc,
                              const float* __restrict__ whh_dec,
                              const float* __restrict__ wih_dec,
                              const float* __restrict__ wfc,
                              unsigned short* __restrict__ whh_bf,
                              unsigned short* __restrict__ weff_bf) {
  int idx = blockIdx.x * 256 + threadIdx.x;
  if (idx >= G4 * Hn) return;
  int r = idx >> 9, c = idx & 511;
  whh_bf[idx] = f2bf(whh_enc[idx]);
  float a = whh_dec[idx];
#pragma unroll
  for (int d = 0; d < 4; d++) a += wih_dec[r * 4 + d] * wfc[d * Hn + c];
  weff_bf[idx] = f2bf(a);
}

// zero d_out (we atomicAdd into it), zero group barriers, build b_eff
__global__ void setup_misc(const float* __restrict__ b_dec,
                           const float* __restrict__ wih_dec,
                           const float* __restrict__ b_fc,
                           float* __restrict__ beff,
                           float* __restrict__ out,
                           unsigned int* __restrict__ bars) {
  int idx = blockIdx.x * 256 + threadIdx.x;
  if (idx < Bn * On) out[idx] = 0.f;
  if (idx < G4) {
    float a = b_dec[idx];
#pragma unroll
    for (int d = 0; d < 4; d++) a += wih_dec[idx * 4 + d] * b_fc[d];
    beff[idx] = a;
  }
  if (idx < 16) bars[idx] = 0u;
}

// ---------------- persistent LSTM kernel ----------------
// 256 blocks x 256 threads, 1 block/CU (LDS-limited).
// group g = blockIdx%16 owns batch rows [64g,64g+64); member jj = blockIdx/16
// owns hidden units [32jj,32jj+32) (gate rows j, 512+j, 1024+j, 1536+j).
// Weight slice (128 rows x 512 K, bf16) lives in LDS, XOR-swizzled.
// h exchanged through global ws as bf16 hi+lo planes, ping-pong buffers,
// group-local monotonic atomic barrier per step.

__global__ void __launch_bounds__(256, 1) lstm_main(
    const float* __restrict__ x,
    const float* __restrict__ wih_enc,
    const float* __restrict__ b_enc,
    const float* __restrict__ wih_dec,
    const float* __restrict__ wfc,
    const float* __restrict__ bfc,
    const unsigned short* __restrict__ whh_bf,
    const unsigned short* __restrict__ weff_bf,
    const float* __restrict__ beff,
    unsigned short* __restrict__ hbuf,   // [2][B*H] hi plane
    unsigned short* __restrict__ lbuf,   // [2][B*H] lo plane
    float* __restrict__ out,
    unsigned int* __restrict__ bars) {
  __shared__ __align__(16) unsigned short wlds[128 * 512];  // 128KB, swizzled
  __shared__ float xw[128][8];    // W_ih_enc strip
  __shared__ float xwd[128][4];   // W_ih_dec strip (delta0 correction)
  __shared__ float biasl[128];
  __shared__ float wfc3s[32];     // W_fc row 3, our hidden slice
  __shared__ float xs[64][8];     // staged x_t for the group's batch tile
  __shared__ float dl0[64][4];    // delta0
  __shared__ float bfc3s;

  const int tid = threadIdx.x;
  const int w = tid >> 6;        // wave id: batch rows [16w,16w+16) of tile
  const int lane = tid & 63;
  const int cidx = lane & 15;    // MFMA col / A-row lane index
  const int kb = lane >> 4;      // k-block 0..3
  const int g = blockIdx.x & 15;
  const int jj = blockIdx.x >> 4;
  const int bb = g * 64;
  unsigned int* bar = bars + g;

  // ---- phase 0: load persistent LDS state, zero own h0 slice ----
  {
    float4* wq4 = (float4*)wlds;
    for (int i = tid; i < 128 * 64; i += 256) {
      int rl = i >> 6, ch = i & 63;
      int gr = (rl >> 5) * 512 + jj * 32 + (rl & 31);
      wq4[rl * 64 + (ch ^ (rl & 7))] = *(const float4*)(whh_bf + (size_t)gr * Hn + ch * 8);
    }
    for (int i = tid; i < 128 * 8; i += 256) {
      int rl = i >> 3, e = i & 7;
      int gr = (rl >> 5) * 512 + jj * 32 + (rl & 31);
      xw[rl][e] = wih_enc[gr * En + e];
    }
    for (int i = tid; i < 128 * 4; i += 256) {
      int rl = i >> 2, d = i & 3;
      int gr = (rl >> 5) * 512 + jj * 32 + (rl & 31);
      xwd[rl][d] = wih_dec[gr * Dn + d];
    }
    for (int i = tid; i < 128; i += 256) {
      int gr = (i >> 5) * 512 + jj * 32 + (i & 31);
      biasl[i] = b_enc[gr];
    }
    if (tid < 32) wfc3s[tid] = wfc[3 * Hn + jj * 32 + tid];
    if (tid == 0) bfc3s = bfc[3];
    for (int i = tid; i < 64 * 32; i += 256) {
      int m = bb + (i >> 5), j = jj * 32 + (i & 31);
      hbuf[(size_t)m * Hn + j] = 0;
      lbuf[(size_t)m * Hn + j] = 0;
    }
  }
  __syncthreads();
  if (tid == 0) __hip_atomic_fetch_add(bar, 1u, __ATOMIC_RELEASE, __HIP_MEMORY_SCOPE_AGENT);
  unsigned int gen = 1;

  float cst[2][4];
#pragma unroll
  for (int a = 0; a < 2; a++)
#pragma unroll
    for (int r = 0; r < 4; r++) cst[a][r] = 0.f;

  const v8s* wq = (const v8s*)wlds;

  // ---- encoder: 168 steps ----
  for (int t = 0; t < Tn; t++) {
    const int cur = t & 1, nxt = cur ^ 1;
    if (tid < 128) {
      int m = tid >> 1, half = tid & 1;
      *(float4*)(&xs[m][half * 4]) =
          *(const float4*)(x + (size_t)(bb + m) * (Tn * En) + t * En + half * 4);
    }
    __syncthreads();
    // acc = bias + x_t @ Wih^T   (f32, overlaps waiting for other wgs)
    v4f acc[8];
#pragma unroll
    for (int nt = 0; nt < 8; nt++) {
      const int rl = nt * 16 + cidx;
      const float bv = biasl[rl];
#pragma unroll
      for (int r = 0; r < 4; r++) {
        float a = bv;
        const int mr = w * 16 + kb * 4 + r;
#pragma unroll
        for (int e = 0; e < 8; e++) a += xs[mr][e] * xw[rl][e];
        acc[nt][r] = a;
      }
    }
    // wait for h_t from all group members
    if (tid == 0) {
      unsigned int tgt = 16u * gen;
      int guard = 0;
      while (__hip_atomic_load(bar, __ATOMIC_ACQUIRE, __HIP_MEMORY_SCOPE_AGENT) < tgt) {
        __builtin_amdgcn_s_sleep(2);
        if (++guard > (1 << 22)) break;
      }
    }
    __syncthreads();
    gen++;
    // gates += h @ Whh^T  (hi + lo bf16 planes, MFMA 16x16x32)
    const unsigned short* hsrc = hbuf + (size_t)cur * HB;
    const unsigned short* lsrc = lbuf + (size_t)cur * HB;
    const int abase = (bb + w * 16 + cidx) * Hn + kb * 8;
    v8s ah[16], al[16];
#pragma unroll
    for (int kt = 0; kt < 16; kt++) {
      ah[kt] = *(const v8s*)(hsrc + abase + kt * 32);
      al[kt] = *(const v8s*)(lsrc + abase + kt * 32);
    }
#pragma unroll
    for (int kt = 0; kt < 16; kt++) {
#pragma unroll
      for (int nt = 0; nt < 8; nt++) {
        const int rl = nt * 16 + cidx;
        v8s bfr = wq[rl * 64 + ((kt * 4 + kb) ^ (rl & 7))];
        acc[nt] = __builtin_amdgcn_mfma_f32_16x16x32_bf16(ah[kt], bfr, acc[nt], 0, 0, 0);
        acc[nt] = __builtin_amdgcn_mfma_f32_16x16x32_bf16(al[kt], bfr, acc[nt], 0, 0, 0);
      }
    }
    // LSTM cell epilogue; write h_{t+1} as hi/lo bf16
    unsigned short* hdst = hbuf + (size_t)nxt * HB;
    unsigned short* ldst = lbuf + (size_t)nxt * HB;
#pragma unroll
    for (int th = 0; th < 2; th++) {
#pragma unroll
      for (int r = 0; r < 4; r++) {
        float iv = acc[0 + th][r], fv = acc[2 + th][r];
        float gv = acc[4 + th][r], ov = acc[6 + th][r];
        float cn = sigm(fv) * cst[th][r] + sigm(iv) * tanh_(gv);
        float hn = sigm(ov) * tanh_(cn);
        cst[th][r] = cn;
        const int m = bb + w * 16 + kb * 4 + r;
        const int j = jj * 32 + th * 16 + cidx;
        unsigned short hh = f2bf(hn);
        hdst[(size_t)m * Hn + j] = hh;
        ldst[(size_t)m * Hn + j] = f2bf(hn - bf2f(hh));
      }
    }
    __syncthreads();
    if (tid == 0) __hip_atomic_fetch_add(bar, 1u, __ATOMIC_RELEASE, __HIP_MEMORY_SCOPE_AGENT);
  }

  // ---- transition: reload LDS with folded decoder weights ----
  {
    float4* wq4 = (float4*)wlds;
    for (int i = tid; i < 128 * 64; i += 256) {
      int rl = i >> 6, ch = i & 63;
      int gr = (rl >> 5) * 512 + jj * 32 + (rl & 31);
      wq4[rl * 64 + (ch ^ (rl & 7))] = *(const float4*)(weff_bf + (size_t)gr * Hn + ch * 8);
    }
    for (int i = tid; i < 128; i += 256) {
      int gr = (i >> 5) * 512 + jj * 32 + (i & 31);
      biasl[i] = beff[gr];
    }
  }

  // ---- decoder: 24 steps (recurrence fully folded; step 0 rank-4 fix) ----
  for (int k = 0; k < On; k++) {
    const int cur = k & 1, nxt = cur ^ 1;
    if (tid == 0) {
      unsigned int tgt = 16u * gen;
      int guard = 0;
      while (__hip_atomic_load(bar, __ATOMIC_ACQUIRE, __HIP_MEMORY_SCOPE_AGENT) < tgt) {
        __builtin_amdgcn_s_sleep(2);
        if (++guard > (1 << 22)) break;
      }
    }
    __syncthreads();
    gen++;
    if (k == 0) {
      // delta0 = x[:,167,4:8] - (h_enc @ Wfc^T + bfc)
      const int row = tid >> 2, d = tid & 3;
      const unsigned short* hr = hbuf + (size_t)(bb + row) * Hn;  // buf 0 = h_enc
      const unsigned short* lr = lbuf + (size_t)(bb + row) * Hn;
      const float* wr = wfc + d * Hn;
      float dot = 0.f;
      for (int kk = 0; kk < Hn; kk++) dot += (bf2f(hr[kk]) + bf2f(lr[kk])) * wr[kk];
      dl0[row][d] = x[(size_t)(bb + row) * (Tn * En) + 167 * En + 4 + d] - (dot + bfc[d]);
      __syncthreads();
    }
    v4f acc[8];
#pragma unroll
    for (int nt = 0; nt < 8; nt++) {
      const int rl = nt * 16 + cidx;
      const float bv = biasl[rl];
#pragma unroll
      for (int r = 0; r < 4; r++) {
        float a = bv;
        if (k == 0) {
          const int mr = w * 16 + kb * 4 + r;
#pragma unroll
          for (int d2 = 0; d2 < 4; d2++) a += dl0[mr][d2] * xwd[rl][d2];
        }
        acc[nt][r] = a;
      }
    }
    const unsigned short* hsrc = hbuf + (size_t)cur * HB;
    const unsigned short* lsrc = lbuf + (size_t)cur * HB;
    const int abase = (bb + w * 16 + cidx) * Hn + kb * 8;
    v8s ah[16], al[16];
#pragma unroll
    for (int kt = 0; kt < 16; kt++) {
      ah[kt] = *(const v8s*)(hsrc + abase + kt * 32);
      al[kt] = *(const v8s*)(lsrc + abase + kt * 32);
    }
#pragma unroll
    for (int kt = 0; kt < 16; kt++) {
#pragma unroll
      for (int nt = 0; nt < 8; nt++) {
        const int rl = nt * 16 + cidx;
        v8s bfr = wq[rl * 64 + ((kt * 4 + kb) ^ (rl & 7))];
        acc[nt] = __builtin_amdgcn_mfma_f32_16x16x32_bf16(ah[kt], bfr, acc[nt], 0, 0, 0);
        acc[nt] = __builtin_amdgcn_mfma_f32_16x16x32_bf16(al[kt], bfr, acc[nt], 0, 0, 0);
      }
    }
    unsigned short* hdst = hbuf + (size_t)nxt * HB;
    unsigned short* ldst = lbuf + (size_t)nxt * HB;
#pragma unroll
    for (int r = 0; r < 4; r++) {
      float hv[2];
#pragma unroll
      for (int th = 0; th < 2; th++) {
        float iv = acc[0 + th][r], fv = acc[2 + th][r];
        float gv = acc[4 + th][r], ov = acc[6 + th][r];
        float cn = sigm(fv) * cst[th][r] + sigm(iv) * tanh_(gv);
        float hn = sigm(ov) * tanh_(cn);
        cst[th][r] = cn;
        hv[th] = hn;
        const int m = bb + w * 16 + kb * 4 + r;
        const int j = jj * 32 + th * 16 + cidx;
        unsigned short hh = f2bf(hn);
        hdst[(size_t)m * Hn + j] = hh;
        ldst[(size_t)m * Hn + j] = f2bf(hn - bf2f(hh));
      }
      // y[:, -1] = h . Wfc[3,:] + bfc[3]  (partial over our 32 hidden units)
      float p = hv[0] * wfc3s[cidx] + hv[1] * wfc3s[16 + cidx];
#pragma unroll
      for (int off = 1; off < 16; off <<= 1) p += __shfl_xor(p, off, 64);
      if (cidx == 0) {
        const int m = bb + w * 16 + kb * 4 + r;
        if (jj == 0) p += bfc3s;
        atomicAdd(out + (size_t)m * On + k, p);
      }
    }
    __syncthreads();
    if (tid == 0) __hip_atomic_fetch_add(bar, 1u, __ATOMIC_RELEASE, __HIP_MEMORY_SCOPE_AGENT);
  }
}

// ---------------- host launch ----------------
extern "C" void kernel_launch(void* const* d_in, const int* in_sizes, int n_in,
                              void* d_out, int out_size, void* d_ws, size_t ws_size,
                              hipStream_t stream) {
  const float* x = (const float*)d_in[0];
  const float* wih_enc = (const float*)d_in[1];
  const float* whh_enc = (const float*)d_in[2];
  const float* b_enc = (const float*)d_in[3];
  const float* wih_dec = (const float*)d_in[4];
  const float* whh_dec = (const float*)d_in[5];
  const float* b_dec = (const float*)d_in[6];
  const float* wfc = (const float*)d_in[7];
  const float* bfc = (const float*)d_in[8];

  char* ws = (char*)d_ws;
  unsigned short* whh_bf = (unsigned short*)ws;                    // 2 MB
  unsigned short* weff_bf = (unsigned short*)(ws + (2u << 20));    // 2 MB
  unsigned short* hbuf = (unsigned short*)(ws + (4u << 20));       // 2 x 1 MB
  unsigned short* lbuf = (unsigned short*)(ws + (6u << 20));       // 2 x 1 MB
  float* beff = (float*)(ws + (8u << 20));                         // 8 KB
  unsigned int* bars = (unsigned int*)(ws + (8u << 20) + 8192);    // 64 B
  float* out = (float*)d_out;

  setup_weights<<<(G4 * Hn) / 256, 256, 0, stream>>>(whh_enc, whh_dec, wih_dec, wfc,
                                                     whh_bf, weff_bf);
  setup_misc<<<(Bn * On) / 256, 256, 0, stream>>>(b_dec, wih_dec, bfc, beff, out, bars);
  lstm_main<<<256, 256, 0, stream>>>(x, wih_enc, b_enc, wih_dec, wfc, bfc,
                                     whh_bf, weff_bf, beff, hbuf, lbuf, out, bars);
}

// Round 2
// 2871.397 us; speedup vs baseline: 1.1874x; 1.1874x over previous
//
#include <hip/hip_runtime.h>

// Problem sizes
#define Bn 1024
#define Tn 168
#define En 8
#define Hn 512
#define Dn 4
#define On 24
#define G4 2048            // 4*H
#define HB (Bn*Hn)         // elements per h buffer plane

typedef short v8s __attribute__((ext_vector_type(8)));
typedef float v4f __attribute__((ext_vector_type(4)));

__device__ __forceinline__ unsigned short f2bf(float f) {
  union { float f; unsigned u; } v; v.f = f;
  return (unsigned short)((v.u + 0x7fffu + ((v.u >> 16) & 1u)) >> 16);
}
__device__ __forceinline__ float bf2f(unsigned short s) {
  union { unsigned u; float f; } v; v.u = ((unsigned)s) << 16; return v.f;
}
__device__ __forceinline__ float sigm(float x) { return 1.f / (1.f + __expf(-x)); }
__device__ __forceinline__ float tanh_(float x) { return 1.f - 2.f / (__expf(2.f * x) + 1.f); }

// Coherent (write-through, L1/L2-bypass) 2-byte store: makes h stores visible
// at the device coherence point WITHOUT needing a release fence (no buffer_wbl2
// L2-drain stall). Ordered before the flag add by an explicit vmcnt(0).
__device__ __forceinline__ void st_short_coh(unsigned short* p, unsigned short v) {
  unsigned long long a = (unsigned long long)p;
  unsigned int vv = v;
  asm volatile("global_store_short %0, %1, off sc0 sc1" :: "v"(a), "v"(vv) : "memory");
}

// ---------------- setup kernels ----------------

// bf16-convert W_hh_enc; build W_eff = W_hh_dec + W_ih_dec @ W_fc (bf16)
__global__ void setup_weights(const float* __restrict__ whh_enc,
                              const float* __restrict__ whh_dec,
                              const float* __restrict__ wih_dec,
                              const float* __restrict__ wfc,
                              unsigned short* __restrict__ whh_bf,
                              unsigned short* __restrict__ weff_bf) {
  int idx = blockIdx.x * 256 + threadIdx.x;
  if (idx >= G4 * Hn) return;
  int r = idx >> 9, c = idx & 511;
  whh_bf[idx] = f2bf(whh_enc[idx]);
  float a = whh_dec[idx];
#pragma unroll
  for (int d = 0; d < 4; d++) a += wih_dec[r * 4 + d] * wfc[d * Hn + c];
  weff_bf[idx] = f2bf(a);
}

// zero d_out (we atomicAdd into it), zero group barriers, build b_eff
__global__ void setup_misc(const float* __restrict__ b_dec,
                           const float* __restrict__ wih_dec,
                           const float* __restrict__ b_fc,
                           float* __restrict__ beff,
                           float* __restrict__ out,
                           unsigned int* __restrict__ bars) {
  int idx = blockIdx.x * 256 + threadIdx.x;
  if (idx < Bn * On) out[idx] = 0.f;
  if (idx < G4) {
    float a = b_dec[idx];
#pragma unroll
    for (int d = 0; d < 4; d++) a += wih_dec[idx * 4 + d] * b_fc[d];
    beff[idx] = a;
  }
  if (idx < 16) bars[idx] = 0u;
}

// ---------------- persistent LSTM kernel ----------------
// 256 blocks x 256 threads, 1 block/CU (LDS-limited).
// group g = blockIdx%16 owns batch rows [64g,64g+64); member jj = blockIdx/16
// owns hidden units [32jj,32jj+32) (gate rows j, 512+j, 1024+j, 1536+j).
// Weight slice (128 rows x 512 K, bf16) lives in LDS, XOR-swizzled.
// h exchanged via COHERENT (sc0 sc1) stores + relaxed flag add (producer) and
// acquire flag load (consumer, buffer_inv) + plain vectorized loads.

__global__ void __launch_bounds__(256, 1) lstm_main(
    const float* __restrict__ x,
    const float* __restrict__ wih_enc,
    const float* __restrict__ b_enc,
    const float* __restrict__ wih_dec,
    const float* __restrict__ wfc,
    const float* __restrict__ bfc,
    const unsigned short* __restrict__ whh_bf,
    const unsigned short* __restrict__ weff_bf,
    const float* __restrict__ beff,
    unsigned short* __restrict__ hbuf,   // [2][B*H] hi plane
    unsigned short* __restrict__ lbuf,   // [2][B*H] lo plane
    float* __restrict__ out,
    unsigned int* __restrict__ bars) {
  __shared__ __align__(16) unsigned short wlds[128 * 512];  // 128KB, swizzled
  __shared__ float xw[128][8];    // W_ih_enc strip
  __shared__ float xwd[128][4];   // W_ih_dec strip (delta0 correction)
  __shared__ float biasl[128];
  __shared__ float wfc3s[32];     // W_fc row 3, our hidden slice
  __shared__ float xs[64][8];     // staged x_t for the group's batch tile
  __shared__ float dl0[64][4];    // delta0
  __shared__ float bfc3s;

  const int tid = threadIdx.x;
  const int w = tid >> 6;        // wave id: batch rows [16w,16w+16) of tile
  const int lane = tid & 63;
  const int cidx = lane & 15;    // MFMA col / A-row lane index
  const int kb = lane >> 4;      // k-block 0..3
  const int g = blockIdx.x & 15;
  const int jj = blockIdx.x >> 4;
  const int bb = g * 64;
  unsigned int* bar = bars + g;

  // ---- phase 0: load persistent LDS state, zero own h0 slice ----
  {
    float4* wq4 = (float4*)wlds;
    for (int i = tid; i < 128 * 64; i += 256) {
      int rl = i >> 6, ch = i & 63;
      int gr = (rl >> 5) * 512 + jj * 32 + (rl & 31);
      wq4[rl * 64 + (ch ^ (rl & 7))] = *(const float4*)(whh_bf + (size_t)gr * Hn + ch * 8);
    }
    for (int i = tid; i < 128 * 8; i += 256) {
      int rl = i >> 3, e = i & 7;
      int gr = (rl >> 5) * 512 + jj * 32 + (rl & 31);
      xw[rl][e] = wih_enc[gr * En + e];
    }
    for (int i = tid; i < 128 * 4; i += 256) {
      int rl = i >> 2, d = i & 3;
      int gr = (rl >> 5) * 512 + jj * 32 + (rl & 31);
      xwd[rl][d] = wih_dec[gr * Dn + d];
    }
    for (int i = tid; i < 128; i += 256) {
      int gr = (i >> 5) * 512 + jj * 32 + (i & 31);
      biasl[i] = b_enc[gr];
    }
    if (tid < 32) wfc3s[tid] = wfc[3 * Hn + jj * 32 + tid];
    if (tid == 0) bfc3s = bfc[3];
    for (int i = tid; i < 64 * 32; i += 256) {
      int m = bb + (i >> 5), j = jj * 32 + (i & 31);
      st_short_coh(hbuf + (size_t)m * Hn + j, 0);
      st_short_coh(lbuf + (size_t)m * Hn + j, 0);
    }
  }
  __syncthreads();
  asm volatile("s_waitcnt vmcnt(0)" ::: "memory");
  if (tid == 0) __hip_atomic_fetch_add(bar, 1u, __ATOMIC_RELAXED, __HIP_MEMORY_SCOPE_AGENT);
  unsigned int gen = 1;

  float cst[2][4];
#pragma unroll
  for (int a = 0; a < 2; a++)
#pragma unroll
    for (int r = 0; r < 4; r++) cst[a][r] = 0.f;

  const v8s* wq = (const v8s*)wlds;

  // ---- encoder: 168 steps ----
  for (int t = 0; t < Tn; t++) {
    const int cur = t & 1, nxt = cur ^ 1;
    if (tid < 128) {
      int m = tid >> 1, half = tid & 1;
      *(float4*)(&xs[m][half * 4]) =
          *(const float4*)(x + (size_t)(bb + m) * (Tn * En) + t * En + half * 4);
    }
    __syncthreads();
    // acc = bias + x_t @ Wih^T   (f32, overlaps waiting for other wgs)
    v4f acc[8];
#pragma unroll
    for (int nt = 0; nt < 8; nt++) {
      const int rl = nt * 16 + cidx;
      const float bv = biasl[rl];
#pragma unroll
      for (int r = 0; r < 4; r++) {
        float a = bv;
        const int mr = w * 16 + kb * 4 + r;
#pragma unroll
        for (int e = 0; e < 8; e++) a += xs[mr][e] * xw[rl][e];
        acc[nt][r] = a;
      }
    }
    // wait for h_t from all group members (relaxed poll, tid0 only)
    if (tid == 0) {
      unsigned int tgt = 16u * gen;
      int guard = 0;
      while (__hip_atomic_load(bar, __ATOMIC_RELAXED, __HIP_MEMORY_SCOPE_AGENT) < tgt) {
        __builtin_amdgcn_s_sleep(2);
        if (++guard > (1 << 22)) break;
      }
    }
    __syncthreads();
    // per-wave acquire (buffer_inv): invalidate stale L1/L2 h lines
    (void)__hip_atomic_load(bar, __ATOMIC_ACQUIRE, __HIP_MEMORY_SCOPE_AGENT);
    gen++;
    // gates += h @ Whh^T  (hi + lo bf16 planes, MFMA 16x16x32)
    const unsigned short* hsrc = hbuf + (size_t)cur * HB;
    const unsigned short* lsrc = lbuf + (size_t)cur * HB;
    const int abase = (bb + w * 16 + cidx) * Hn + kb * 8;
    v8s ah[16], al[16];
#pragma unroll
    for (int kt = 0; kt < 16; kt++) {
      ah[kt] = *(const v8s*)(hsrc + abase + kt * 32);
      al[kt] = *(const v8s*)(lsrc + abase + kt * 32);
    }
#pragma unroll
    for (int kt = 0; kt < 16; kt++) {
#pragma unroll
      for (int nt = 0; nt < 8; nt++) {
        const int rl = nt * 16 + cidx;
        v8s bfr = wq[rl * 64 + ((kt * 4 + kb) ^ (rl & 7))];
        acc[nt] = __builtin_amdgcn_mfma_f32_16x16x32_bf16(ah[kt], bfr, acc[nt], 0, 0, 0);
        acc[nt] = __builtin_amdgcn_mfma_f32_16x16x32_bf16(al[kt], bfr, acc[nt], 0, 0, 0);
      }
    }
    // LSTM cell epilogue; write h_{t+1} as hi/lo bf16 (coherent stores)
    unsigned short* hdst = hbuf + (size_t)nxt * HB;
    unsigned short* ldst = lbuf + (size_t)nxt * HB;
#pragma unroll
    for (int th = 0; th < 2; th++) {
#pragma unroll
      for (int r = 0; r < 4; r++) {
        float iv = acc[0 + th][r], fv = acc[2 + th][r];
        float gv = acc[4 + th][r], ov = acc[6 + th][r];
        float cn = sigm(fv) * cst[th][r] + sigm(iv) * tanh_(gv);
        float hn = sigm(ov) * tanh_(cn);
        cst[th][r] = cn;
        const int m = bb + w * 16 + kb * 4 + r;
        const int j = jj * 32 + th * 16 + cidx;
        unsigned short hh = f2bf(hn);
        st_short_coh(hdst + (size_t)m * Hn + j, hh);
        st_short_coh(ldst + (size_t)m * Hn + j, f2bf(hn - bf2f(hh)));
      }
    }
    __syncthreads();
    asm volatile("s_waitcnt vmcnt(0)" ::: "memory");
    if (tid == 0) __hip_atomic_fetch_add(bar, 1u, __ATOMIC_RELAXED, __HIP_MEMORY_SCOPE_AGENT);
  }

  // ---- transition: reload LDS with folded decoder weights ----
  {
    float4* wq4 = (float4*)wlds;
    for (int i = tid; i < 128 * 64; i += 256) {
      int rl = i >> 6, ch = i & 63;
      int gr = (rl >> 5) * 512 + jj * 32 + (rl & 31);
      wq4[rl * 64 + (ch ^ (rl & 7))] = *(const float4*)(weff_bf + (size_t)gr * Hn + ch * 8);
    }
    for (int i = tid; i < 128; i += 256) {
      int gr = (i >> 5) * 512 + jj * 32 + (i & 31);
      biasl[i] = beff[gr];
    }
  }

  // ---- decoder: 24 steps (recurrence fully folded; step 0 rank-4 fix) ----
  for (int k = 0; k < On; k++) {
    const int cur = k & 1, nxt = cur ^ 1;
    if (tid == 0) {
      unsigned int tgt = 16u * gen;
      int guard = 0;
      while (__hip_atomic_load(bar, __ATOMIC_RELAXED, __HIP_MEMORY_SCOPE_AGENT) < tgt) {
        __builtin_amdgcn_s_sleep(2);
        if (++guard > (1 << 22)) break;
      }
    }
    __syncthreads();
    (void)__hip_atomic_load(bar, __ATOMIC_ACQUIRE, __HIP_MEMORY_SCOPE_AGENT);
    gen++;
    if (k == 0) {
      // delta0 = x[:,167,4:8] - (h_enc @ Wfc^T + bfc)
      const int row = tid >> 2, d = tid & 3;
      const unsigned short* hr = hbuf + (size_t)(bb + row) * Hn;  // buf 0 = h_enc
      const unsigned short* lr = lbuf + (size_t)(bb + row) * Hn;
      const float* wr = wfc + d * Hn;
      float dot = 0.f;
      for (int kk = 0; kk < Hn; kk++) dot += (bf2f(hr[kk]) + bf2f(lr[kk])) * wr[kk];
      dl0[row][d] = x[(size_t)(bb + row) * (Tn * En) + 167 * En + 4 + d] - (dot + bfc[d]);
      __syncthreads();
    }
    v4f acc[8];
#pragma unroll
    for (int nt = 0; nt < 8; nt++) {
      const int rl = nt * 16 + cidx;
      const float bv = biasl[rl];
#pragma unroll
      for (int r = 0; r < 4; r++) {
        float a = bv;
        if (k == 0) {
          const int mr = w * 16 + kb * 4 + r;
#pragma unroll
          for (int d2 = 0; d2 < 4; d2++) a += dl0[mr][d2] * xwd[rl][d2];
        }
        acc[nt][r] = a;
      }
    }
    const unsigned short* hsrc = hbuf + (size_t)cur * HB;
    const unsigned short* lsrc = lbuf + (size_t)cur * HB;
    const int abase = (bb + w * 16 + cidx) * Hn + kb * 8;
    v8s ah[16], al[16];
#pragma unroll
    for (int kt = 0; kt < 16; kt++) {
      ah[kt] = *(const v8s*)(hsrc + abase + kt * 32);
      al[kt] = *(const v8s*)(lsrc + abase + kt * 32);
    }
#pragma unroll
    for (int kt = 0; kt < 16; kt++) {
#pragma unroll
      for (int nt = 0; nt < 8; nt++) {
        const int rl = nt * 16 + cidx;
        v8s bfr = wq[rl * 64 + ((kt * 4 + kb) ^ (rl & 7))];
        acc[nt] = __builtin_amdgcn_mfma_f32_16x16x32_bf16(ah[kt], bfr, acc[nt], 0, 0, 0);
        acc[nt] = __builtin_amdgcn_mfma_f32_16x16x32_bf16(al[kt], bfr, acc[nt], 0, 0, 0);
      }
    }
    unsigned short* hdst = hbuf + (size_t)nxt * HB;
    unsigned short* ldst = lbuf + (size_t)nxt * HB;
#pragma unroll
    for (int r = 0; r < 4; r++) {
      float hv[2];
#pragma unroll
      for (int th = 0; th < 2; th++) {
        float iv = acc[0 + th][r], fv = acc[2 + th][r];
        float gv = acc[4 + th][r], ov = acc[6 + th][r];
        float cn = sigm(fv) * cst[th][r] + sigm(iv) * tanh_(gv);
        float hn = sigm(ov) * tanh_(cn);
        cst[th][r] = cn;
        hv[th] = hn;
        const int m = bb + w * 16 + kb * 4 + r;
        const int j = jj * 32 + th * 16 + cidx;
        unsigned short hh = f2bf(hn);
        st_short_coh(hdst + (size_t)m * Hn + j, hh);
        st_short_coh(ldst + (size_t)m * Hn + j, f2bf(hn - bf2f(hh)));
      }
      // y[:, -1] = h . Wfc[3,:] + bfc[3]  (partial over our 32 hidden units)
      float p = hv[0] * wfc3s[cidx] + hv[1] * wfc3s[16 + cidx];
#pragma unroll
      for (int off = 1; off < 16; off <<= 1) p += __shfl_xor(p, off, 64);
      if (cidx == 0) {
        const int m = bb + w * 16 + kb * 4 + r;
        if (jj == 0) p += bfc3s;
        atomicAdd(out + (size_t)m * On + k, p);
      }
    }
    __syncthreads();
    asm volatile("s_waitcnt vmcnt(0)" ::: "memory");
    if (tid == 0) __hip_atomic_fetch_add(bar, 1u, __ATOMIC_RELAXED, __HIP_MEMORY_SCOPE_AGENT);
  }
}

// ---------------- host launch ----------------
extern "C" void kernel_launch(void* const* d_in, const int* in_sizes, int n_in,
                              void* d_out, int out_size, void* d_ws, size_t ws_size,
                              hipStream_t stream) {
  const float* x = (const float*)d_in[0];
  const float* wih_enc = (const float*)d_in[1];
  const float* whh_enc = (const float*)d_in[2];
  const float* b_enc = (const float*)d_in[3];
  const float* wih_dec = (const float*)d_in[4];
  const float* whh_dec = (const float*)d_in[5];
  const float* b_dec = (const float*)d_in[6];
  const float* wfc = (const float*)d_in[7];
  const float* bfc = (const float*)d_in[8];

  char* ws = (char*)d_ws;
  unsigned short* whh_bf = (unsigned short*)ws;                    // 2 MB
  unsigned short* weff_bf = (unsigned short*)(ws + (2u << 20));    // 2 MB
  unsigned short* hbuf = (unsigned short*)(ws + (4u << 20));       // 2 x 1 MB
  unsigned short* lbuf = (unsigned short*)(ws + (6u << 20));       // 2 x 1 MB
  float* beff = (float*)(ws + (8u << 20));                         // 8 KB
  unsigned int* bars = (unsigned int*)(ws + (8u << 20) + 8192);    // 64 B
  float* out = (float*)d_out;

  setup_weights<<<(G4 * Hn) / 256, 256, 0, stream>>>(whh_enc, whh_dec, wih_dec, wfc,
                                                     whh_bf, weff_bf);
  setup_misc<<<(Bn * On) / 256, 256, 0, stream>>>(b_dec, wih_dec, bfc, beff, out, bars);
  lstm_main<<<256, 256, 0, stream>>>(x, wih_enc, b_enc, wih_dec, wfc, bfc,
                                     whh_bf, weff_bf, beff, hbuf, lbuf, out, bars);
}

// Round 3
// 1521.851 us; speedup vs baseline: 2.2404x; 1.8868x over previous
//
#include <hip/hip_runtime.h>

// Problem sizes
#define Bn 1024
#define Tn 168
#define En 8
#define Hn 512
#define Dn 4
#define On 24
#define G4 2048            // 4*H
#define HB (Bn*Hn)         // elements per h buffer plane

typedef short v8s __attribute__((ext_vector_type(8)));
typedef float v4f __attribute__((ext_vector_type(4)));

__device__ __forceinline__ unsigned short f2bf(float f) {
  union { float f; unsigned u; } v; v.f = f;
  return (unsigned short)((v.u + 0x7fffu + ((v.u >> 16) & 1u)) >> 16);
}
__device__ __forceinline__ float bf2f(unsigned short s) {
  union { unsigned u; float f; } v; v.u = ((unsigned)s) << 16; return v.f;
}
__device__ __forceinline__ float sigm(float x) { return 1.f / (1.f + __expf(-x)); }
__device__ __forceinline__ float tanh_(float x) { return 1.f - 2.f / (__expf(2.f * x) + 1.f); }

// Coherent (L1/L2-bypass) ops: data moves through the device coherence point,
// so no release-wbl2 / acquire-inv fences are ever needed.
__device__ __forceinline__ void st_short_coh(unsigned short* p, unsigned short v) {
  unsigned int vv = v;
  asm volatile("global_store_short %0, %1, off sc0 sc1" :: "v"(p), "v"(vv) : "memory");
}
__device__ __forceinline__ void st_dword_coh(unsigned* p, unsigned v) {
  asm volatile("global_store_dword %0, %1, off sc0 sc1" :: "v"(p), "v"(v) : "memory");
}
__device__ __forceinline__ unsigned ld_u_coh(const unsigned* p) {
  unsigned v;
  asm volatile("global_load_dword %0, %1, off sc0 sc1\n\ts_waitcnt vmcnt(0)"
               : "=v"(v) : "v"(p) : "memory");
  return v;
}
__device__ __forceinline__ float ld_f_coh(const float* p) {
  float v;
  asm volatile("global_load_dword %0, %1, off sc0 sc1\n\ts_waitcnt vmcnt(0)"
               : "=v"(v) : "v"(p) : "memory");
  return v;
}
// coherent 16B fragment load, NO wait (pipelined; waits done via WAITV)
#define LDC(dst, p) \
  asm volatile("global_load_dwordx4 %0, %1, off sc0 sc1" : "=&v"(dst) : "v"(p))
#define WAITV(N) do { \
  asm volatile("s_waitcnt vmcnt(" #N ")" ::: "memory"); \
  __builtin_amdgcn_sched_barrier(0); } while (0)

// ---------------- setup kernels ----------------

__global__ void setup_weights(const float* __restrict__ whh_enc,
                              const float* __restrict__ whh_dec,
                              const float* __restrict__ wih_dec,
                              const float* __restrict__ wfc,
                              unsigned short* __restrict__ whh_bf,
                              unsigned short* __restrict__ weff_bf) {
  int idx = blockIdx.x * 256 + threadIdx.x;
  if (idx >= G4 * Hn) return;
  int r = idx >> 9, c = idx & 511;
  whh_bf[idx] = f2bf(whh_enc[idx]);
  float a = whh_dec[idx];
#pragma unroll
  for (int d = 0; d < 4; d++) a += wih_dec[r * 4 + d] * wfc[d * Hn + c];
  weff_bf[idx] = f2bf(a);
}

// zero d_out, flags, dpart; build b_eff
__global__ void setup_misc(const float* __restrict__ b_dec,
                           const float* __restrict__ wih_dec,
                           const float* __restrict__ b_fc,
                           float* __restrict__ beff,
                           float* __restrict__ out,
                           unsigned int* __restrict__ flags,
                           float* __restrict__ dpart) {
  int idx = blockIdx.x * 256 + threadIdx.x;
  if (idx < Bn * On) out[idx] = 0.f;
  if (idx < G4) {
    float a = b_dec[idx];
#pragma unroll
    for (int d = 0; d < 4; d++) a += wih_dec[idx * 4 + d] * b_fc[d];
    beff[idx] = a;
  }
  if (idx < 256 * 64) flags[idx] = 0u;   // 256 flags, 256B stride
  if (idx < 16 * 64 * 4) dpart[idx] = 0.f;
}

// ---------------- persistent LSTM kernel ----------------
// 256 blocks x 256 threads, 1 block/CU. group g = blockIdx%16 owns batch rows
// [64g,64g+64); member jj = blockIdx/16 owns hidden units [32jj,32jj+32).
// Exchange protocol: per-member monotonic flag (value = # of h's produced);
// h written with coherent 2B stores, read with coherent dwordx4; consuming h_t
// requires flag[q] >= t+1 for all q. 2 ping-pong buffers suffice (flag t+1
// certifies consumption of h_{t-1}). No block barrier in the steady state.

__global__ void __launch_bounds__(256, 1) lstm_main(
    const float* __restrict__ x,
    const float* __restrict__ wih_enc,
    const float* __restrict__ b_enc,
    const float* __restrict__ wih_dec,
    const float* __restrict__ wfc,
    const float* __restrict__ bfc,
    const unsigned short* __restrict__ whh_bf,
    const unsigned short* __restrict__ weff_bf,
    const float* __restrict__ beff,
    unsigned short* __restrict__ hbuf,   // [2][B*H] hi plane
    unsigned short* __restrict__ lbuf,   // [2][B*H] lo plane
    float* __restrict__ out,
    unsigned int* __restrict__ flags,    // 256 x 64 u32 (256B stride)
    float* __restrict__ dpart) {         // [16][64][4] partial h_enc@Wfc^T
  __shared__ __align__(16) unsigned short wlds[128 * 512];  // 128KB, swizzled
  __shared__ float xw[128][8];
  __shared__ float xwd[128][4];
  __shared__ float biasl[128];
  __shared__ float wfcs[4][32];   // W_fc rows 0..3, our hidden slice
  __shared__ float xs[4][16][8];  // per-wave x strip (no cross-wave use)
  __shared__ float dl0[64][4];
  __shared__ float bfc3s;
  __shared__ unsigned scnt;       // monotonic per-block wave-completion counter

  const int tid = threadIdx.x;
  const int w = tid >> 6;
  const int lane = tid & 63;
  const int cidx = lane & 15;
  const int kb = lane >> 4;
  const int sw = cidx & 7;
  const int g = blockIdx.x & 15;
  const int jj = blockIdx.x >> 4;
  const int bb = g * 64;
  unsigned* myflag = flags + (((g << 4) + jj) << 6);
  const unsigned* fpoll = flags + (((g << 4) + (lane & 15)) << 6);

  // ---- phase 0 ----
  {
    if (tid == 0) scnt = 0u;
    float4* wq4 = (float4*)wlds;
    for (int i = tid; i < 128 * 64; i += 256) {
      int rl = i >> 6, ch = i & 63;
      int gr = (rl >> 5) * 512 + jj * 32 + (rl & 31);
      wq4[rl * 64 + (ch ^ (rl & 7))] = *(const float4*)(whh_bf + (size_t)gr * Hn + ch * 8);
    }
    for (int i = tid; i < 128 * 8; i += 256) {
      int rl = i >> 3, e = i & 7;
      int gr = (rl >> 5) * 512 + jj * 32 + (rl & 31);
      xw[rl][e] = wih_enc[gr * En + e];
    }
    for (int i = tid; i < 128 * 4; i += 256) {
      int rl = i >> 2, d = i & 3;
      int gr = (rl >> 5) * 512 + jj * 32 + (rl & 31);
      xwd[rl][d] = wih_dec[gr * Dn + d];
    }
    for (int i = tid; i < 128; i += 256) {
      int gr = (i >> 5) * 512 + jj * 32 + (i & 31);
      biasl[i] = b_enc[gr];
    }
    if (tid < 128) wfcs[tid >> 5][tid & 31] = wfc[(tid >> 5) * Hn + jj * 32 + (tid & 31)];
    if (tid == 0) bfc3s = bfc[3];
    for (int i = tid; i < 64 * 32; i += 256) {
      int m = bb + (i >> 5), j = jj * 32 + (i & 31);
      st_short_coh(hbuf + (size_t)m * Hn + j, 0);
      st_short_coh(lbuf + (size_t)m * Hn + j, 0);
    }
  }
  asm volatile("s_waitcnt vmcnt(0)" ::: "memory");
  __syncthreads();
  if (tid == 0) st_dword_coh(myflag, 1u);   // h_0 available

  float cst[2][4];
#pragma unroll
  for (int a = 0; a < 2; a++)
#pragma unroll
    for (int r = 0; r < 4; r++) cst[a][r] = 0.f;

  const v8s* wq = (const v8s*)wlds;
  const int abase = (bb + w * 16 + cidx) * Hn + kb * 8;

#define POLL(TGT) do { \
    int guard = 0; \
    while (true) { \
      unsigned fv = ld_u_coh(fpoll); \
      if (__ballot(fv < (unsigned)(TGT)) == 0ull) break; \
      __builtin_amdgcn_s_sleep(1); \
      if (++guard > (1 << 21)) break; \
    } } while (0)

#define ISSUE(AH, AL, K0) \
  _Pragma("unroll") for (int q = 0; q < 4; q++) { \
    LDC(AH[q], (const v8s*)(hsrc + abase + (K0 + q) * 32)); \
    LDC(AL[q], (const v8s*)(lsrc + abase + (K0 + q) * 32)); }

#define MMC(AH, AL, K0) \
  _Pragma("unroll") for (int q = 0; q < 4; q++) \
    _Pragma("unroll") for (int nt = 0; nt < 8; nt++) { \
      v8s bfr = wq[(nt * 16 + cidx) * 64 + ((((K0 + q) * 4) + kb) ^ sw)]; \
      acc[nt] = __builtin_amdgcn_mfma_f32_16x16x32_bf16(AH[q], bfr, acc[nt], 0, 0, 0); \
      acc[nt] = __builtin_amdgcn_mfma_f32_16x16x32_bf16(AL[q], bfr, acc[nt], 0, 0, 0); }

#define HMATMUL(CUR) do { \
    const unsigned short* hsrc = hbuf + (size_t)(CUR) * HB; \
    const unsigned short* lsrc = lbuf + (size_t)(CUR) * HB; \
    v8s a0h[4], a0l[4], a1h[4], a1l[4]; \
    ISSUE(a0h, a0l, 0) ISSUE(a1h, a1l, 4) \
    WAITV(8); MMC(a0h, a0l, 0) \
    ISSUE(a0h, a0l, 8) \
    WAITV(8); MMC(a1h, a1l, 4) \
    ISSUE(a1h, a1l, 12) \
    WAITV(8); MMC(a0h, a0l, 8) \
    WAITV(0); MMC(a1h, a1l, 12) \
  } while (0)

  // ---- encoder: 168 steps ----
  for (int t = 0; t < Tn; t++) {
    const int cur = t & 1, nxt = cur ^ 1;
    // per-wave x staging (wave-private LDS strip; no barrier)
    {
      int row = lane >> 2, p2 = lane & 3;
      const float* xp = x + (size_t)(bb + w * 16 + row) * (Tn * En) + t * En + p2 * 2;
      float2 xv = *(const float2*)xp;
      xs[w][row][p2 * 2] = xv.x;
      xs[w][row][p2 * 2 + 1] = xv.y;
      asm volatile("s_waitcnt lgkmcnt(0)" ::: "memory");
    }
    v4f acc[8];
#pragma unroll
    for (int nt = 0; nt < 8; nt++) {
      const int rl = nt * 16 + cidx;
      const float bv = biasl[rl];
#pragma unroll
      for (int r = 0; r < 4; r++) {
        float a = bv;
#pragma unroll
        for (int e = 0; e < 8; e++) a += xs[w][kb * 4 + r][e] * xw[rl][e];
        acc[nt][r] = a;
      }
    }
    POLL(t + 1);
    HMATMUL(cur);
    // epilogue
    unsigned short* hdst = hbuf + (size_t)nxt * HB;
    unsigned short* ldst = lbuf + (size_t)nxt * HB;
#pragma unroll
    for (int r = 0; r < 4; r++) {
      float hv[2];
#pragma unroll
      for (int th = 0; th < 2; th++) {
        float iv = acc[0 + th][r], fv = acc[2 + th][r];
        float gv = acc[4 + th][r], ov = acc[6 + th][r];
        float cn = sigm(fv) * cst[th][r] + sigm(iv) * tanh_(gv);
        float hn = sigm(ov) * tanh_(cn);
        cst[th][r] = cn;
        hv[th] = hn;
        const int m = bb + w * 16 + kb * 4 + r;
        const int j = jj * 32 + th * 16 + cidx;
        unsigned short hh = f2bf(hn);
        st_short_coh(hdst + (size_t)m * Hn + j, hh);
        st_short_coh(ldst + (size_t)m * Hn + j, f2bf(hn - bf2f(hh)));
      }
      if (t == Tn - 1) {
        // partial h_enc @ Wfc^T over our 32 hidden cols -> dpart
#pragma unroll
        for (int d = 0; d < 4; d++) {
          float s = hv[0] * wfcs[d][cidx] + hv[1] * wfcs[d][16 + cidx];
          s += __shfl_xor(s, 1, 64); s += __shfl_xor(s, 2, 64);
          s += __shfl_xor(s, 4, 64); s += __shfl_xor(s, 8, 64);
          if (cidx == 0)
            atomicAdd(dpart + ((g * 64 + w * 16 + kb * 4 + r) * 4 + d), s);
        }
      }
    }
    asm volatile("s_waitcnt vmcnt(0)" ::: "memory");
    if (lane == 0) {
      unsigned old = atomicAdd(&scnt, 1u);
      if ((old & 3u) == 3u) st_dword_coh(myflag, (unsigned)(t + 2));
    }
  }

  // ---- transition: reload LDS with folded decoder weights ----
  __syncthreads();
  {
    float4* wq4 = (float4*)wlds;
    for (int i = tid; i < 128 * 64; i += 256) {
      int rl = i >> 6, ch = i & 63;
      int gr = (rl >> 5) * 512 + jj * 32 + (rl & 31);
      wq4[rl * 64 + (ch ^ (rl & 7))] = *(const float4*)(weff_bf + (size_t)gr * Hn + ch * 8);
    }
    for (int i = tid; i < 128; i += 256) {
      int gr = (i >> 5) * 512 + jj * 32 + (i & 31);
      biasl[i] = beff[gr];
    }
  }
  __syncthreads();

  // ---- decoder: 24 steps ----
  for (int k = 0; k < On; k++) {
    const int T = Tn + k;
    const int cur = k & 1, nxt = cur ^ 1;
    POLL(T + 1);
    if (k == 0) {
      // dl0 = x[:,167,4:8] - (sum of member partials + bfc)
      int row = tid >> 2, d = tid & 3;
      float pv = ld_f_coh(dpart + ((g * 64 + row) * 4 + d));
      float xv = x[(size_t)(bb + row) * (Tn * En) + 167 * En + 4 + d];
      dl0[row][d] = xv - (pv + bfc[d]);
      __syncthreads();
    }
    v4f acc[8];
#pragma unroll
    for (int nt = 0; nt < 8; nt++) {
      const int rl = nt * 16 + cidx;
      const float bv = biasl[rl];
#pragma unroll
      for (int r = 0; r < 4; r++) {
        float a = bv;
        if (k == 0) {
#pragma unroll
          for (int d2 = 0; d2 < 4; d2++)
            a += dl0[w * 16 + kb * 4 + r][d2] * xwd[rl][d2];
        }
        acc[nt][r] = a;
      }
    }
    HMATMUL(cur);
    unsigned short* hdst = hbuf + (size_t)nxt * HB;
    unsigned short* ldst = lbuf + (size_t)nxt * HB;
#pragma unroll
    for (int r = 0; r < 4; r++) {
      float hv[2];
#pragma unroll
      for (int th = 0; th < 2; th++) {
        float iv = acc[0 + th][r], fv = acc[2 + th][r];
        float gv = acc[4 + th][r], ov = acc[6 + th][r];
        float cn = sigm(fv) * cst[th][r] + sigm(iv) * tanh_(gv);
        float hn = sigm(ov) * tanh_(cn);
        cst[th][r] = cn;
        hv[th] = hn;
        const int m = bb + w * 16 + kb * 4 + r;
        const int j = jj * 32 + th * 16 + cidx;
        unsigned short hh = f2bf(hn);
        st_short_coh(hdst + (size_t)m * Hn + j, hh);
        st_short_coh(ldst + (size_t)m * Hn + j, f2bf(hn - bf2f(hh)));
      }
      // y[:, -1] partial over our 32 hidden units
      float p = hv[0] * wfcs[3][cidx] + hv[1] * wfcs[3][16 + cidx];
      p += __shfl_xor(p, 1, 64); p += __shfl_xor(p, 2, 64);
      p += __shfl_xor(p, 4, 64); p += __shfl_xor(p, 8, 64);
      if (cidx == 0) {
        const int m = bb + w * 16 + kb * 4 + r;
        float pp = p + (jj == 0 ? bfc3s : 0.f);
        atomicAdd(out + (size_t)m * On + k, pp);
      }
    }
    asm volatile("s_waitcnt vmcnt(0)" ::: "memory");
    if (lane == 0) {
      unsigned old = atomicAdd(&scnt, 1u);
      if ((old & 3u) == 3u) st_dword_coh(myflag, (unsigned)(T + 2));
    }
  }
}

// ---------------- host launch ----------------
extern "C" void kernel_launch(void* const* d_in, const int* in_sizes, int n_in,
                              void* d_out, int out_size, void* d_ws, size_t ws_size,
                              hipStream_t stream) {
  const float* x = (const float*)d_in[0];
  const float* wih_enc = (const float*)d_in[1];
  const float* whh_enc = (const float*)d_in[2];
  const float* b_enc = (const float*)d_in[3];
  const float* wih_dec = (const float*)d_in[4];
  const float* whh_dec = (const float*)d_in[5];
  const float* b_dec = (const float*)d_in[6];
  const float* wfc = (const float*)d_in[7];
  const float* bfc = (const float*)d_in[8];

  char* ws = (char*)d_ws;
  unsigned short* whh_bf = (unsigned short*)ws;                      // 2 MB
  unsigned short* weff_bf = (unsigned short*)(ws + (2u << 20));      // 2 MB
  unsigned short* hbuf = (unsigned short*)(ws + (4u << 20));         // 2 x 1 MB
  unsigned short* lbuf = (unsigned short*)(ws + (6u << 20));         // 2 x 1 MB
  float* beff = (float*)(ws + (8u << 20));                           // 8 KB
  unsigned int* flags = (unsigned int*)(ws + (8u << 20) + 8192);     // 64 KB
  float* dpart = (float*)(ws + (8u << 20) + 8192 + 65536);           // 16 KB
  float* out = (float*)d_out;

  setup_weights<<<(G4 * Hn) / 256, 256, 0, stream>>>(whh_enc, whh_dec, wih_dec, wfc,
                                                     whh_bf, weff_bf);
  setup_misc<<<(Bn * On) / 256, 256, 0, stream>>>(b_dec, wih_dec, bfc, beff, out,
                                                  flags, dpart);
  lstm_main<<<256, 256, 0, stream>>>(x, wih_enc, b_enc, wih_dec, wfc, bfc,
                                     whh_bf, weff_bf, beff, hbuf, lbuf, out,
                                     flags, dpart);
}

// Round 6
// 1473.782 us; speedup vs baseline: 2.3134x; 1.0326x over previous
//
#include <hip/hip_runtime.h>

// Problem sizes
#define Bn 1024
#define Tn 168
#define En 8
#define Hn 512
#define Dn 4
#define On 24
#define G4 2048            // 4*H
#define HB (Bn*Hn)         // elements per h buffer plane

typedef short v8s __attribute__((ext_vector_type(8)));
typedef float v4f __attribute__((ext_vector_type(4)));

#define CAT2(a, b) a##b

__device__ __forceinline__ unsigned short f2bf(float f) {
  union { float f; unsigned u; } v; v.f = f;
  return (unsigned short)((v.u + 0x7fffu + ((v.u >> 16) & 1u)) >> 16);
}
__device__ __forceinline__ float bf2f(unsigned short s) {
  union { unsigned u; float f; } v; v.u = ((unsigned)s) << 16; return v.f;
}
__device__ __forceinline__ float sigm(float x) { return 1.f / (1.f + __expf(-x)); }
__device__ __forceinline__ float tanh_(float x) { return 1.f - 2.f / (__expf(2.f * x) + 1.f); }

// ---- flag / control ops: ALWAYS device-coherent (sc0 sc1 = MALL side).
// Proven in round 3: stores ordered by vmcnt(0) before flag; polls always
// read the coherence point -> no stale-clean-L2 livelock possible.
#define STFLAG(p, v) do { unsigned __vv = (v); \
  asm volatile("global_store_dword %0, %1, off sc0 sc1" :: "v"(p), "v"(__vv) : "memory"); } while (0)
#define LDFLAG(r, p) asm volatile("global_load_dword %0, %1, off sc0 sc1\n\ts_waitcnt vmcnt(0)" \
  : "=v"(r) : "v"(p) : "memory")

// ---- h-plane data ops: path-specialized.
// D=0 (fast, group co-located on one XCD): plain stores (dirty in shared L2),
//   sc0 loads (L1 bypass, L2 hit). D=1 (slow): device-coherent sc0 sc1.
#define STH_0(p, v) do { unsigned __vv = (v); \
  asm volatile("global_store_short %0, %1, off" :: "v"(p), "v"(__vv) : "memory"); } while (0)
#define STH_1(p, v) do { unsigned __vv = (v); \
  asm volatile("global_store_short %0, %1, off sc0 sc1" :: "v"(p), "v"(__vv) : "memory"); } while (0)
#define LDC_0(dst, p) asm volatile("global_load_dwordx4 %0, %1, off sc0" : "=&v"(dst) : "v"(p))
#define LDC_1(dst, p) asm volatile("global_load_dwordx4 %0, %1, off sc0 sc1" : "=&v"(dst) : "v"(p))

#define WAITV(N) do { \
  asm volatile("s_waitcnt vmcnt(" #N ")" ::: "memory"); \
  __builtin_amdgcn_sched_barrier(0); } while (0)

// ---------------- setup kernels ----------------

__global__ void setup_weights(const float* __restrict__ whh_enc,
                              const float* __restrict__ whh_dec,
                              const float* __restrict__ wih_dec,
                              const float* __restrict__ wfc,
                              unsigned short* __restrict__ whh_bf,
                              unsigned short* __restrict__ weff_bf) {
  int idx = blockIdx.x * 256 + threadIdx.x;
  if (idx >= G4 * Hn) return;
  int r = idx >> 9, c = idx & 511;
  whh_bf[idx] = f2bf(whh_enc[idx]);
  float a = whh_dec[idx];
#pragma unroll
  for (int d = 0; d < 4; d++) a += wih_dec[r * 4 + d] * wfc[d * Hn + c];
  weff_bf[idx] = f2bf(a);
}

__global__ void setup_misc(const float* __restrict__ b_dec,
                           const float* __restrict__ wih_dec,
                           const float* __restrict__ b_fc,
                           float* __restrict__ beff,
                           float* __restrict__ out,
                           unsigned int* __restrict__ flags,
                           float* __restrict__ dpart) {
  int idx = blockIdx.x * 256 + threadIdx.x;
  if (idx < Bn * On) out[idx] = 0.f;
  if (idx < G4) {
    float a = b_dec[idx];
#pragma unroll
    for (int d = 0; d < 4; d++) a += wih_dec[idx * 4 + d] * b_fc[d];
    beff[idx] = a;
  }
  if (idx < 256 * 64) flags[idx] = 0u;   // 256 flags, 256B stride
  if (idx < 16 * 64 * 4) dpart[idx] = 0.f;
}

// ---------------- persistent LSTM kernel ----------------
// 256 blocks x 256 threads, 1 block/CU. group g = blockIdx%16 owns batch rows
// [64g,64g+64); member jj = blockIdx/16 owns hidden units [32jj,32jj+32).
// Flag protocol (round-3 proven, always device-coherent): flag value = number
// of h states produced; step t polls >= t+1, produces h_{t+1}, sets t+2.
// h-plane path chosen at runtime: if all 16 members report the same
// HW_REG_XCC_ID, h moves through the shared XCD L2 (plain store / sc0 load);
// otherwise through the coherence point (sc0 sc1), as in round 3.

__global__ void __launch_bounds__(256, 1) lstm_main(
    const float* __restrict__ x,
    const float* __restrict__ wih_enc,
    const float* __restrict__ b_enc,
    const float* __restrict__ wih_dec,
    const float* __restrict__ wfc,
    const float* __restrict__ bfc,
    const unsigned short* __restrict__ whh_bf,
    const unsigned short* __restrict__ weff_bf,
    const float* __restrict__ beff,
    unsigned short* __restrict__ hbuf,   // [2][B*H] hi plane
    unsigned short* __restrict__ lbuf,   // [2][B*H] lo plane
    float* __restrict__ out,
    unsigned int* __restrict__ flags,    // 256 x 64 u32 (256B stride)
    unsigned int* __restrict__ xcds,     // 256 u32: member -> XCC id
    float* __restrict__ dpart) {         // [16][64][4] partial h_enc@Wfc^T
  __shared__ __align__(16) unsigned short wlds[128 * 512];  // 128KB, swizzled
  __shared__ float xw[128][8];
  __shared__ float xwd[128][4];
  __shared__ float biasl[128];
  __shared__ float wfcs[4][32];
  __shared__ float xs[4][16][8];
  __shared__ float dl0[64][4];
  __shared__ float bfc3s;
  __shared__ unsigned scnt;

  const int tid = threadIdx.x;
  const int w = tid >> 6;
  const int lane = tid & 63;
  const int cidx = lane & 15;
  const int kb = lane >> 4;
  const int sw = cidx & 7;
  const int g = blockIdx.x & 15;
  const int jj = blockIdx.x >> 4;
  const int bb = g * 64;
  unsigned* myflag = flags + (((g << 4) + jj) << 6);
  const unsigned* fpoll = flags + (((g << 4) + (lane & 15)) << 6);

  unsigned xcc;
  asm volatile("s_getreg_b32 %0, hwreg(HW_REG_XCC_ID)" : "=s"(xcc));

  // ---- phase 0: LDS fills + h zeroing (sc1) + xcds publish ----
  {
    if (tid == 0) scnt = 0u;
    float4* wq4 = (float4*)wlds;
    for (int i = tid; i < 128 * 64; i += 256) {
      int rl = i >> 6, ch = i & 63;
      int gr = (rl >> 5) * 512 + jj * 32 + (rl & 31);
      wq4[rl * 64 + (ch ^ (rl & 7))] = *(const float4*)(whh_bf + (size_t)gr * Hn + ch * 8);
    }
    for (int i = tid; i < 128 * 8; i += 256) {
      int rl = i >> 3, e = i & 7;
      int gr = (rl >> 5) * 512 + jj * 32 + (rl & 31);
      xw[rl][e] = wih_enc[gr * En + e];
    }
    for (int i = tid; i < 128 * 4; i += 256) {
      int rl = i >> 2, d = i & 3;
      int gr = (rl >> 5) * 512 + jj * 32 + (rl & 31);
      xwd[rl][d] = wih_dec[gr * Dn + d];
    }
    for (int i = tid; i < 128; i += 256) {
      int gr = (i >> 5) * 512 + jj * 32 + (i & 31);
      biasl[i] = b_enc[gr];
    }
    if (tid < 128) wfcs[tid >> 5][tid & 31] = wfc[(tid >> 5) * Hn + jj * 32 + (tid & 31)];
    if (tid == 0) bfc3s = bfc[3];
    // zero own h0 slice, device-coherent (works for both consumer paths)
    for (int i = tid; i < 64 * 32; i += 256) {
      int m = bb + (i >> 5), j = jj * 32 + (i & 31);
      STH_1(hbuf + (size_t)m * Hn + j, 0);
      STH_1(lbuf + (size_t)m * Hn + j, 0);
    }
    if (tid == 0) {
      unsigned* xp = xcds + ((g << 4) + jj);
      asm volatile("global_store_dword %0, %1, off sc0 sc1" :: "v"(xp), "v"(xcc) : "memory");
    }
  }
  asm volatile("s_waitcnt vmcnt(0)" ::: "memory");
  __syncthreads();
  if (tid == 0) STFLAG(myflag, 1u);   // h_0 + xcds available

#define POLL(TGT) do { \
    int guard = 0; unsigned fv; \
    while (true) { \
      LDFLAG(fv, fpoll); \
      if (__ballot(fv < (unsigned)(TGT)) == 0ull) break; \
      __builtin_amdgcn_s_sleep(1); \
      if (++guard > (1 << 21)) break; \
    } } while (0)

  // ---- co-location check (flags >= 1 certifies xcds stores complete) ----
  POLL(1);
  unsigned other;
  {
    const unsigned* xq = xcds + ((g << 4) + (lane & 15));
    asm volatile("global_load_dword %0, %1, off sc0 sc1\n\ts_waitcnt vmcnt(0)"
                 : "=v"(other) : "v"(xq) : "memory");
  }
  const int fast = (__ballot(other != xcc) == 0ull) ? 1 : 0;

  float cst[2][4];
#pragma unroll
  for (int a = 0; a < 2; a++)
#pragma unroll
    for (int r = 0; r < 4; r++) cst[a][r] = 0.f;

  const v8s* wq = (const v8s*)wlds;
  const int abase = (bb + w * 16 + cidx) * Hn + kb * 8;

#define ISSUEX(D, AH, AL, K0) \
  _Pragma("unroll") for (int q = 0; q < 4; q++) { \
    CAT2(LDC_, D)(AH[q], (const v8s*)(hsrc + abase + (K0 + q) * 32)); \
    CAT2(LDC_, D)(AL[q], (const v8s*)(lsrc + abase + (K0 + q) * 32)); }

#define MMC(AH, AL, K0) \
  _Pragma("unroll") for (int q = 0; q < 4; q++) \
    _Pragma("unroll") for (int nt = 0; nt < 8; nt++) { \
      v8s bfr = wq[(nt * 16 + cidx) * 64 + ((((K0 + q) * 4) + kb) ^ sw)]; \
      acc[nt] = __builtin_amdgcn_mfma_f32_16x16x32_bf16(AH[q], bfr, acc[nt], 0, 0, 0); \
      acc[nt] = __builtin_amdgcn_mfma_f32_16x16x32_bf16(AL[q], bfr, acc[nt], 0, 0, 0); }

#define HMATMULX(D, CUR) do { \
    const unsigned short* hsrc = hbuf + (size_t)(CUR) * HB; \
    const unsigned short* lsrc = lbuf + (size_t)(CUR) * HB; \
    v8s a0h[4], a0l[4], a1h[4], a1l[4]; \
    ISSUEX(D, a0h, a0l, 0) ISSUEX(D, a1h, a1l, 4) \
    WAITV(8); MMC(a0h, a0l, 0) \
    ISSUEX(D, a0h, a0l, 8) \
    WAITV(8); MMC(a1h, a1l, 4) \
    ISSUEX(D, a1h, a1l, 12) \
    WAITV(8); MMC(a0h, a0l, 8) \
    WAITV(0); MMC(a1h, a1l, 12) \
  } while (0)

#define ENC_STEP(D, t) do { \
    const int cur = (t) & 1, nxt = cur ^ 1; \
    { int row = lane >> 2, p2 = lane & 3; \
      const float* xp = x + (size_t)(bb + w * 16 + row) * (Tn * En) + (t) * En + p2 * 2; \
      float2 xv = *(const float2*)xp; \
      xs[w][row][p2 * 2] = xv.x; xs[w][row][p2 * 2 + 1] = xv.y; \
      asm volatile("s_waitcnt lgkmcnt(0)" ::: "memory"); } \
    v4f acc[8]; \
    _Pragma("unroll") for (int nt = 0; nt < 8; nt++) { \
      const int rl = nt * 16 + cidx; const float bv = biasl[rl]; \
      _Pragma("unroll") for (int r = 0; r < 4; r++) { \
        float a = bv; \
        _Pragma("unroll") for (int e = 0; e < 8; e++) a += xs[w][kb * 4 + r][e] * xw[rl][e]; \
        acc[nt][r] = a; } } \
    POLL((t) + 1); \
    HMATMULX(D, cur); \
    unsigned short* hdst = hbuf + (size_t)nxt * HB; \
    unsigned short* ldst = lbuf + (size_t)nxt * HB; \
    _Pragma("unroll") for (int r = 0; r < 4; r++) { \
      float hv[2]; \
      _Pragma("unroll") for (int th = 0; th < 2; th++) { \
        float iv = acc[0 + th][r], fv2 = acc[2 + th][r]; \
        float gv = acc[4 + th][r], ov = acc[6 + th][r]; \
        float cn = sigm(fv2) * cst[th][r] + sigm(iv) * tanh_(gv); \
        float hn = sigm(ov) * tanh_(cn); \
        cst[th][r] = cn; hv[th] = hn; \
        const int m = bb + w * 16 + kb * 4 + r; \
        const int j = jj * 32 + th * 16 + cidx; \
        unsigned short hh = f2bf(hn); \
        CAT2(STH_, D)(hdst + (size_t)m * Hn + j, hh); \
        CAT2(STH_, D)(ldst + (size_t)m * Hn + j, f2bf(hn - bf2f(hh))); } \
      if ((t) == Tn - 1) { \
        _Pragma("unroll") for (int d = 0; d < 4; d++) { \
          float s = hv[0] * wfcs[d][cidx] + hv[1] * wfcs[d][16 + cidx]; \
          s += __shfl_xor(s, 1, 64); s += __shfl_xor(s, 2, 64); \
          s += __shfl_xor(s, 4, 64); s += __shfl_xor(s, 8, 64); \
          if (cidx == 0) \
            atomicAdd(dpart + ((g * 64 + w * 16 + kb * 4 + r) * 4 + d), s); } } } \
    asm volatile("s_waitcnt vmcnt(0)" ::: "memory"); \
    if (lane == 0) { \
      unsigned old = atomicAdd(&scnt, 1u); \
      if ((old & 3u) == 3u) STFLAG(myflag, (unsigned)((t) + 2)); } \
  } while (0)

#define DEC_STEP(D, k) do { \
    const int T = Tn + (k); \
    const int cur = (k) & 1, nxt = cur ^ 1; \
    POLL(T + 1); \
    if ((k) == 0) { \
      int row = tid >> 2, d = tid & 3; \
      float pv; \
      asm volatile("global_load_dword %0, %1, off sc0 sc1\n\ts_waitcnt vmcnt(0)" \
                   : "=v"(pv) : "v"(dpart + ((g * 64 + row) * 4 + d)) : "memory"); \
      float xv = x[(size_t)(bb + row) * (Tn * En) + 167 * En + 4 + d]; \
      dl0[row][d] = xv - (pv + bfc[d]); \
      __syncthreads(); \
    } \
    v4f acc[8]; \
    _Pragma("unroll") for (int nt = 0; nt < 8; nt++) { \
      const int rl = nt * 16 + cidx; const float bv = biasl[rl]; \
      _Pragma("unroll") for (int r = 0; r < 4; r++) { \
        float a = bv; \
        if ((k) == 0) { \
          _Pragma("unroll") for (int d2 = 0; d2 < 4; d2++) \
            a += dl0[w * 16 + kb * 4 + r][d2] * xwd[rl][d2]; } \
        acc[nt][r] = a; } } \
    HMATMULX(D, cur); \
    unsigned short* hdst = hbuf + (size_t)nxt * HB; \
    unsigned short* ldst = lbuf + (size_t)nxt * HB; \
    _Pragma("unroll") for (int r = 0; r < 4; r++) { \
      float hv[2]; \
      _Pragma("unroll") for (int th = 0; th < 2; th++) { \
        float iv = acc[0 + th][r], fv2 = acc[2 + th][r]; \
        float gv = acc[4 + th][r], ov = acc[6 + th][r]; \
        float cn = sigm(fv2) * cst[th][r] + sigm(iv) * tanh_(gv); \
        float hn = sigm(ov) * tanh_(cn); \
        cst[th][r] = cn; hv[th] = hn; \
        const int m = bb + w * 16 + kb * 4 + r; \
        const int j = jj * 32 + th * 16 + cidx; \
        unsigned short hh = f2bf(hn); \
        CAT2(STH_, D)(hdst + (size_t)m * Hn + j, hh); \
        CAT2(STH_, D)(ldst + (size_t)m * Hn + j, f2bf(hn - bf2f(hh))); } \
      float p = hv[0] * wfcs[3][cidx] + hv[1] * wfcs[3][16 + cidx]; \
      p += __shfl_xor(p, 1, 64); p += __shfl_xor(p, 2, 64); \
      p += __shfl_xor(p, 4, 64); p += __shfl_xor(p, 8, 64); \
      if (cidx == 0) { \
        const int m = bb + w * 16 + kb * 4 + r; \
        float pp = p + (jj == 0 ? bfc3s : 0.f); \
        atomicAdd(out + (size_t)m * On + (k), pp); } } \
    asm volatile("s_waitcnt vmcnt(0)" ::: "memory"); \
    if (lane == 0) { \
      unsigned old = atomicAdd(&scnt, 1u); \
      if ((old & 3u) == 3u) STFLAG(myflag, (unsigned)(T + 2)); } \
  } while (0)

  // ---- encoder ----
  if (fast) {
    for (int t = 0; t < Tn; t++) ENC_STEP(0, t);
  } else {
    for (int t = 0; t < Tn; t++) ENC_STEP(1, t);
  }

  // ---- transition: reload LDS with folded decoder weights ----
  __syncthreads();
  {
    float4* wq4 = (float4*)wlds;
    for (int i = tid; i < 128 * 64; i += 256) {
      int rl = i >> 6, ch = i & 63;
      int gr = (rl >> 5) * 512 + jj * 32 + (rl & 31);
      wq4[rl * 64 + (ch ^ (rl & 7))] = *(const float4*)(weff_bf + (size_t)gr * Hn + ch * 8);
    }
    for (int i = tid; i < 128; i += 256) {
      int gr = (i >> 5) * 512 + jj * 32 + (i & 31);
      biasl[i] = beff[gr];
    }
  }
  __syncthreads();

  // ---- decoder ----
  if (fast) {
    for (int k = 0; k < On; k++) DEC_STEP(0, k);
  } else {
    for (int k = 0; k < On; k++) DEC_STEP(1, k);
  }
}

// ---------------- host launch ----------------
extern "C" void kernel_launch(void* const* d_in, const int* in_sizes, int n_in,
                              void* d_out, int out_size, void* d_ws, size_t ws_size,
                              hipStream_t stream) {
  const float* x = (const float*)d_in[0];
  const float* wih_enc = (const float*)d_in[1];
  const float* whh_enc = (const float*)d_in[2];
  const float* b_enc = (const float*)d_in[3];
  const float* wih_dec = (const float*)d_in[4];
  const float* whh_dec = (const float*)d_in[5];
  const float* b_dec = (const float*)d_in[6];
  const float* wfc = (const float*)d_in[7];
  const float* bfc = (const float*)d_in[8];

  char* ws = (char*)d_ws;
  unsigned short* whh_bf = (unsigned short*)ws;                      // 2 MB
  unsigned short* weff_bf = (unsigned short*)(ws + (2u << 20));      // 2 MB
  unsigned short* hbuf = (unsigned short*)(ws + (4u << 20));         // 2 x 1 MB
  unsigned short* lbuf = (unsigned short*)(ws + (6u << 20));         // 2 x 1 MB
  float* beff = (float*)(ws + (8u << 20));                           // 8 KB
  unsigned int* flags = (unsigned int*)(ws + (8u << 20) + 8192);     // 64 KB
  unsigned int* xcds = (unsigned int*)(ws + (8u << 20) + 8192 + 65536);  // 1 KB
  float* dpart = (float*)(ws + (8u << 20) + 8192 + 65536 + 1024);    // 16 KB
  float* out = (float*)d_out;

  setup_weights<<<(G4 * Hn) / 256, 256, 0, stream>>>(whh_enc, whh_dec, wih_dec, wfc,
                                                     whh_bf, weff_bf);
  setup_misc<<<(Bn * On) / 256, 256, 0, stream>>>(b_dec, wih_dec, bfc, beff, out,
                                                  flags, dpart);
  lstm_main<<<256, 256, 0, stream>>>(x, wih_enc, b_enc, wih_dec, wfc, bfc,
                                     whh_bf, weff_bf, beff, hbuf, lbuf, out,
                                     flags, xcds, dpart);
}